// Round 1
// baseline (195.630 us; speedup 1.0000x reference)
//
#include <hip/hip_runtime.h>

#define NDIM 2048
#define FDIM 64
#define KDIM 8
#define BDIM 32

// ---------------------------------------------------------------------------
// K1: cov_k = L_k @ L_k^T + diag(sr_k^2), written into out[k] (k = 0..7).
// Grid: (N/128, N/128, K). Block: 256 threads (16x16), 8x8 micro-tile,
// strip-mined (gn = n0 + ty + 16*i) so LDS reads are 2-way-conflict max.
// LDS: two 128x68-padded f32 panels (68 KB) -> 2 blocks/CU.
// ---------------------------------------------------------------------------
__global__ __launch_bounds__(256) void rfm_cov_kernel(
    const float* __restrict__ L, const float* __restrict__ sr,
    float* __restrict__ out)
{
    __shared__ float An[128][68];
    __shared__ float Am[128][68];

    const int k  = blockIdx.z;
    const int n0 = blockIdx.y * 128;
    const int m0 = blockIdx.x * 128;
    const float* Lk = L + (size_t)k * NDIM * FDIM;
    const int t = threadIdx.x;

    // Stage both panels: 128 rows x 64 f = 2048 float4 per panel, 8 per thread.
    #pragma unroll
    for (int r = 0; r < 8; ++r) {
        const int idx = t + r * 256;       // float4 index within panel
        const int row = idx >> 4;          // 16 float4 per row
        const int fc  = (idx & 15) << 2;
        const float4 va = *(const float4*)&Lk[(size_t)(n0 + row) * FDIM + fc];
        *(float4*)&An[row][fc] = va;
        const float4 vb = *(const float4*)&Lk[(size_t)(m0 + row) * FDIM + fc];
        *(float4*)&Am[row][fc] = vb;
    }
    __syncthreads();

    const int tx = t & 15;
    const int ty = t >> 4;

    float acc[8][8];
    #pragma unroll
    for (int i = 0; i < 8; ++i)
        #pragma unroll
        for (int j = 0; j < 8; ++j) acc[i][j] = 0.0f;

    #pragma unroll 2
    for (int f = 0; f < FDIM; f += 4) {
        float4 a[8], b[8];
        #pragma unroll
        for (int i = 0; i < 8; ++i)
            a[i] = *(const float4*)&An[ty + 16 * i][f];
        #pragma unroll
        for (int j = 0; j < 8; ++j)
            b[j] = *(const float4*)&Am[tx + 16 * j][f];
        #pragma unroll
        for (int i = 0; i < 8; ++i)
            #pragma unroll
            for (int j = 0; j < 8; ++j)
                acc[i][j] += a[i].x * b[j].x + a[i].y * b[j].y
                           + a[i].z * b[j].z + a[i].w * b[j].w;
    }

    // Epilogue: add diagonal sr^2, store (lanes tx-consecutive -> coalesced).
    #pragma unroll
    for (int i = 0; i < 8; ++i) {
        const int gn = n0 + ty + 16 * i;
        float* orow = out + ((size_t)k * NDIM + gn) * NDIM;
        #pragma unroll
        for (int j = 0; j < 8; ++j) {
            const int gm = m0 + tx + 16 * j;
            float v = acc[i][j];
            if (gn == gm) {
                const float q = sr[k * NDIM + gn];
                v += q * q;
            }
            orow[gm] = v;
        }
    }
}

// ---------------------------------------------------------------------------
// K2: out[b] = sum_k p[b,k] * cov_k, reading cov from out[0..7] and writing
// all 32 b-planes (including overwriting the cov slots). Each thread owns one
// float4 of the (n,m) plane: reads-before-writes within the thread, and no
// other block ever touches this (n,m) position -> no hazard, deterministic.
// ---------------------------------------------------------------------------
__global__ __launch_bounds__(256) void rfm_mix_kernel(
    const float* __restrict__ p, float* __restrict__ out)
{
    __shared__ float pl[BDIM * KDIM];
    const int t = threadIdx.x;
    if (t < BDIM * KDIM) pl[t] = p[t];
    __syncthreads();

    const size_t NN  = (size_t)NDIM * NDIM;
    const size_t pos = ((size_t)blockIdx.x * 256 + t) * 4;

    float4 c[KDIM];
    #pragma unroll
    for (int k = 0; k < KDIM; ++k)
        c[k] = *(const float4*)(out + (size_t)k * NN + pos);

    #pragma unroll
    for (int b = 0; b < BDIM; ++b) {
        float4 r = make_float4(0.f, 0.f, 0.f, 0.f);
        #pragma unroll
        for (int k = 0; k < KDIM; ++k) {
            const float s = pl[b * KDIM + k];
            r.x += s * c[k].x;
            r.y += s * c[k].y;
            r.z += s * c[k].z;
            r.w += s * c[k].w;
        }
        *(float4*)(out + (size_t)b * NN + pos) = r;
    }
}

extern "C" void kernel_launch(void* const* d_in, const int* in_sizes, int n_in,
                              void* d_out, int out_size, void* d_ws, size_t ws_size,
                              hipStream_t stream)
{
    const float* p  = (const float*)d_in[0];   // (B,K) = (32,8)
    const float* L  = (const float*)d_in[1];   // (K,N,F) = (8,2048,64)
    const float* sr = (const float*)d_in[2];   // (K,N)   = (8,2048)
    float* out = (float*)d_out;                // (B,N,N) = (32,2048,2048)

    dim3 g1(NDIM / 128, NDIM / 128, KDIM);
    hipLaunchKernelGGL(rfm_cov_kernel, g1, dim3(256), 0, stream, L, sr, out);

    dim3 g2((unsigned)((NDIM * (size_t)NDIM / 4) / 256));
    hipLaunchKernelGGL(rfm_mix_kernel, g2, dim3(256), 0, stream, p, out);
}